// Round 4
// baseline (156.346 us; speedup 1.0000x reference)
//
#include <hip/hip_runtime.h>
#include <stdint.h>
#include <math.h>

// Problem constants (from reference)
#define NB 16
#define NK 16384
#define NADD 32
#define NP 36            // 2^RANK + ADD = 4 + 32
#define DIM 65536        // IN_DIM == OUT_DIM

// Round-17 (= round-16 resubmit after container infra failure):
// 256 blocks x 1024 threads, 128 KB LDS accumulator, 1 block/CU
// (128 KB < 160 KB LDS/CU). 16 waves/CU = 4 waves/SIMD -- same wave
// occupancy as the old 2x512 geometry, but:
//   * groups per batch row 32 -> 16  => partials 64 MB -> 32 MB
//   * output chunks 4 -> 2           => half the scatter predication passes
//   * f2 reduction loop 32 -> 16 rows
#define TPB 1024
#define GPB 16           // groups per batch row (NK / TPB)
#define NCH 2            // output chunks per batch row
#define CHW 32768        // chunk width (floats) -> 128 KB LDS accumulator

typedef float f32x4 __attribute__((ext_vector_type(4)));
typedef float f32x8 __attribute__((ext_vector_type(8)));
typedef unsigned int u32x2 __attribute__((ext_vector_type(2)));
typedef unsigned int u32x4 __attribute__((ext_vector_type(4)));

// LDS-only barrier: orders DS ops without draining vmcnt -- global partial
// stores have no intra-kernel consumer, so they stay in flight across passes.
#define BAR_LGKM() asm volatile("s_waitcnt lgkmcnt(0)\n\ts_barrier" ::: "memory")

__device__ __forceinline__ uint32_t rotl32(uint32_t x, uint32_t r) {
    return (x << r) | (x >> (32u - r));
}

// Threefry-2x32 (20 rounds), key = (0, 42); partitionable mode: ctr=(0,idx),
// bits = out0 ^ out1. CONFIRMED bit-correct (rounds 1-15). INDEX-CRITICAL:
// do not touch.
__device__ __forceinline__ uint32_t tf_bits(uint32_t idx) {
    const uint32_t K1 = 42u;
    const uint32_t K2 = 0x1BD11BDAu ^ 42u;
    uint32_t x0 = 0u;
    uint32_t x1 = idx + K1;
#define TF_ROUND(r) { x0 += x1; x1 = rotl32(x1, r); x1 ^= x0; }
#define TF_G(a,b,c,d) TF_ROUND(a) TF_ROUND(b) TF_ROUND(c) TF_ROUND(d)
    TF_G(13,15,26,6)   x0 += K1;  x1 += K2 + 1u;
    TF_G(17,29,16,24)  x0 += K2;  x1 += 2u;
    TF_G(13,15,26,6)              x1 += K1 + 3u;
    TF_G(17,29,16,24)  x0 += K1;  x1 += K2 + 4u;
    TF_G(13,15,26,6)   x0 += K2;  x1 += 5u;
#undef TF_G
#undef TF_ROUND
    return x0 ^ x1;
}

// Bit-exact XLA:CPU f32 exp (Cephes/Eigen pexp), strict per-op f32 rounding,
// no FMA contraction. CONFIRMED: rounds 3-15 passed. INDEX-CRITICAL (feeds
// sigmoid -> means -> floor/ceil indices): do not touch.
__device__ __forceinline__ float xla_expf(float x0) {
    float x = fminf(fmaxf(x0, -88.3762626647949f), 88.3762626647950f);
    const float fx = floorf(__fadd_rn(__fmul_rn(x, 1.44269504088896341f), 0.5f));
    const float tmp = __fmul_rn(fx, 0.693359375f);
    float z = __fmul_rn(fx, -2.12194440e-4f);
    float r = __fsub_rn(x, tmp);
    r = __fsub_rn(r, z);
    z = __fmul_rn(r, r);
    float y = 1.9875691500E-4f;
    y = __fadd_rn(__fmul_rn(y, r), 1.3981999507E-3f);
    y = __fadd_rn(__fmul_rn(y, r), 8.3334519073E-3f);
    y = __fadd_rn(__fmul_rn(y, r), 4.1665795894E-2f);
    y = __fadd_rn(__fmul_rn(y, r), 1.6666665459E-1f);
    y = __fadd_rn(__fmul_rn(y, r), 5.0000001201E-1f);
    y = __fadd_rn(__fmul_rn(y, z), r);
    y = __fadd_rn(y, 1.0f);
    const int n = (int)fx;
    const float p2n = __uint_as_float((uint32_t)(n + 127) << 23);
    return fmaxf(__fmul_rn(y, p2n), x0);
}

// bf16 RNE pack of two f32 into one u32 (a -> low 16, b -> high 16)
__device__ __forceinline__ uint32_t bf16pair(float a, float b) {
    uint32_t ua = __float_as_uint(a), ub = __float_as_uint(b);
    ua = (ua + 0x7FFFu + ((ua >> 16) & 1u)) >> 16;
    ub = (ub + 0x7FFFu + ((ub >> 16) & 1u)) >> 16;
    return ua | (ub << 16);
}

// ------- primary: 256x1024, 128 KB LDS (2 passes), bf16 partials (32 MB) --
// Partial layout: row = DIM bf16 = 32768 u32 -> row offset = blk << 15 (u32);
// chunk c = 32768 bf16 = 16384 u32 = 8192 u32x2.
// tid -> (b, k) mapping identical to all passing rounds (global point id).

__global__ __launch_bounds__(TPB, 4) void f1_gen_reduce_bf16(
    const float*  __restrict__ x,     // (NB, DIM)
    const float4* __restrict__ res4,  // (NB, NK, 4)
    uint32_t* __restrict__ part)      // [NB*GPB][DIM] bf16
{
    __shared__ float acc[CHW];        // 128 KB -> 1 block/CU, 16 waves
    f32x4* const acc4 = reinterpret_cast<f32x4*>(acc);
    const int blk = blockIdx.x;       // [0, 256)
    const uint32_t tid = (uint32_t)blk * TPB + threadIdx.x;  // global point id
    const int b = (int)(tid >> 14);
    const float* __restrict__ xrow = x + ((size_t)b << 16);

    // zero LDS up front so the pre-scatter barrier costs nothing
    // 8192 f32x4 / 1024 threads = 8 iters
    #pragma unroll
    for (int j = 0; j < 8; ++j)
        acc4[j * TPB + threadIdx.x] = (f32x4)(0.0f);

    const float4 r = res4[tid];

    // ---- index-critical means ----
    const float e0 = xla_expf(-r.x);
    const float e1 = xla_expf(-r.y);
    const float s0 = __fdiv_rn(1.0f, __fadd_rn(1.0f, e0));
    const float s1 = __fdiv_rn(1.0f, __fadd_rn(1.0f, e1));
    const float m0 = __fmul_rn(s0, 65535.0f);   // INDEX-CRITICAL
    const float m1 = __fmul_rn(s1, 65535.0f);   // INDEX-CRITICAL

    // sigma feeds weights only -> relaxed transcendentals
    const float a2 = r.z + 2.0f;
    const float sp = fmaxf(a2, 0.0f) + log1pf(__expf(-fabsf(a2)));
    const float sigma = (sp + 1e-6f) * 65536.0f;
    const float inv_sig = __builtin_amdgcn_rcpf(sigma);
    const float n2 = -0.5f * inv_sig * inv_sig;
    const float val = r.w;

    uint32_t packed[NP];   // (out16 << 16) | in16
    float    xv[NP];       // gathered x values, issued as indices appear

    // corners: indices + immediate gather issue
    {
        const float f0 = floorf(m0), c0 = ceilf(m0);
        const float f1v = floorf(m1), c1 = ceilf(m1);
        const uint32_t uf0 = (uint32_t)(int)f0, uc0 = (uint32_t)(int)c0;
        const uint32_t uf1 = (uint32_t)(int)f1v, uc1 = (uint32_t)(int)c1;
        packed[0] = (uf0 << 16) | uf1;  xv[0] = xrow[uf1];
        packed[1] = (uf0 << 16) | uc1;  xv[1] = xrow[uc1];
        packed[2] = (uc0 << 16) | uf1;  xv[2] = xrow[uf1];
        packed[3] = (uc0 << 16) | uc1;  xv[3] = xrow[uc1];
    }

    // sampled tuples: threefry VALU work hides gather latency
    const float ONE_MEPS = (float)(1.0 - 1e-6);
    const uint32_t base = tid * 64u;
    #pragma unroll
    for (int a = 0; a < NADD; ++a) {
        const uint32_t bb0 = tf_bits(base + 2u*(uint32_t)a);
        const uint32_t bb1 = tf_bits(base + 2u*(uint32_t)a + 1u);
        const float u0 = __fmul_rn(__uint_as_float((bb0 >> 9) | 0x3f800000u) - 1.0f, ONE_MEPS);
        const float u1 = __fmul_rn(__uint_as_float((bb1 >> 9) | 0x3f800000u) - 1.0f, ONE_MEPS);
        const float s0f = floorf(__fmul_rn(u0, 65536.0f));  // INDEX-CRITICAL
        const float s1f = floorf(__fmul_rn(u1, 65536.0f));  // INDEX-CRITICAL
        const uint32_t pi = ((uint32_t)(int)s0f << 16) | (uint32_t)(int)s1f;
        packed[4 + a] = pi;
        xv[4 + a] = xrow[pi & 0xFFFFu];
    }

    // exp pass: denom uses raw e (same order as passing kernels)
    float w[NP];
    float denom = 0.0f;
    #pragma unroll
    for (int p = 0; p < NP; ++p) {
        const float d0 = (float)(int)(packed[p] >> 16) - m0;
        const float d1 = (float)(int)(packed[p] & 0xFFFFu) - m1;
        const float e = __expf(n2 * fmaf(d1, d1, d0 * d0));
        denom += e + 1e-6f;
        w[p] = e * xv[p];
    }
    const float scale = __fdiv_rn(val, denom);
    #pragma unroll
    for (int p = 0; p < NP; ++p) w[p] *= scale;

    __syncthreads();   // zeros visible; no global stores outstanding yet

    uint32_t* __restrict__ dst = part + ((size_t)blk << 15);  // u32 row
    #pragma unroll 1
    for (uint32_t c = 0; c < NCH; ++c) {
        #pragma unroll
        for (int p = 0; p < NP; ++p) {
            if ((packed[p] >> 31) == c)               // chunk = out >> 15
                atomicAdd(&acc[(packed[p] >> 16) & (CHW - 1)], w[p]);
        }
        BAR_LGKM();   // DS atomics drained; global stores may stay in flight
        // merged drain: pack bf16, cacheable store, re-zero in one sweep.
        // chunk = 8192 u32x2; 8192/1024 = 8 iters
        u32x2* __restrict__ dst2 =
            reinterpret_cast<u32x2*>(dst + (size_t)c * 16384);
        #pragma unroll
        for (int j = 0; j < 8; ++j) {
            const int idx = j * TPB + (int)threadIdx.x;   // [0, 8192) u32x2
            const f32x4 v = acc4[idx];
            const u32x2 o = { bf16pair(v.x, v.y), bf16pair(v.z, v.w) };
            dst2[idx] = o;                                // LLC-resident
            acc4[idx] = (f32x4)(0.0f);                    // re-zero for next pass
        }
        BAR_LGKM();   // re-zeros visible; stores not drained
    }
    // kernel-end release flushes outstanding stores before f2 launches
}

// F2: y = bias + sum_g bf16 part rows (now 16 rows); fully coalesced.
__global__ __launch_bounds__(256) void f2_final_bf16(
    const u32x4* __restrict__ part4,  // [NB*GPB][8192] u32x4
    const f32x8* __restrict__ bias8,  // 8192 x f32x8
    f32x8* __restrict__ y8)           // NB*8192 x f32x8
{
    const int i = blockIdx.x * 256 + threadIdx.x;  // [0, NB*DIM/8)
    const int o8 = i & 8191;                       // u32x4 index within row
    const int b = i >> 13;
    f32x8 s = bias8[o8];
    #pragma unroll
    for (int g = 0; g < GPB; ++g) {
        const u32x4 p = part4[(((size_t)(b * GPB + g)) << 13) + o8];
        s[0] += __uint_as_float(p.x << 16);
        s[1] += __uint_as_float(p.x & 0xFFFF0000u);
        s[2] += __uint_as_float(p.y << 16);
        s[3] += __uint_as_float(p.y & 0xFFFF0000u);
        s[4] += __uint_as_float(p.z << 16);
        s[5] += __uint_as_float(p.z & 0xFFFF0000u);
        s[6] += __uint_as_float(p.w << 16);
        s[7] += __uint_as_float(p.w & 0xFFFF0000u);
    }
    __builtin_nontemporal_store(s, &y8[i]);
}

// ---------------- fallback path (round-3 passing kernel) ----------------

__device__ __forceinline__ void gen_point(const float4 r, uint32_t tid,
                                          uint32_t* packed, float* w) {
    const float e0 = xla_expf(-r.x);
    const float e1 = xla_expf(-r.y);
    const float s0 = __fdiv_rn(1.0f, __fadd_rn(1.0f, e0));
    const float s1 = __fdiv_rn(1.0f, __fadd_rn(1.0f, e1));
    const float m0 = __fmul_rn(s0, 65535.0f);
    const float m1 = __fmul_rn(s1, 65535.0f);
    const float a2 = r.z + 2.0f;
    const float sp = fmaxf(a2, 0.0f) + log1pf(__expf(-fabsf(a2)));
    const float sigma = (sp + 1e-6f) * 65536.0f;
    const float inv_sig = __builtin_amdgcn_rcpf(sigma);
    const float n2 = -0.5f * inv_sig * inv_sig;
    const float val = r.w;

    const float f0 = floorf(m0), c0 = ceilf(m0);
    const float f1 = floorf(m1), c1 = ceilf(m1);
    {
        const float cd0[4] = {f0, f0, c0, c0};
        const float cd1[4] = {f1, c1, f1, c1};
        #pragma unroll
        for (int p = 0; p < 4; ++p) {
            const float d0 = cd0[p] - m0;
            const float d1 = cd1[p] - m1;
            w[p] = __expf(n2 * fmaf(d1, d1, d0 * d0));
            packed[p] = ((uint32_t)(int)cd0[p] << 16) | (uint32_t)(int)cd1[p];
        }
    }
    const float ONE_MEPS = (float)(1.0 - 1e-6);
    const uint32_t base = tid * 64u;
    #pragma unroll
    for (int a = 0; a < NADD; ++a) {
        const uint32_t bb0 = tf_bits(base + 2u*(uint32_t)a);
        const uint32_t bb1 = tf_bits(base + 2u*(uint32_t)a + 1u);
        const float u0 = __fmul_rn(__uint_as_float((bb0 >> 9) | 0x3f800000u) - 1.0f, ONE_MEPS);
        const float u1 = __fmul_rn(__uint_as_float((bb1 >> 9) | 0x3f800000u) - 1.0f, ONE_MEPS);
        const float s0f = floorf(__fmul_rn(u0, 65536.0f));
        const float s1f = floorf(__fmul_rn(u1, 65536.0f));
        const float d0 = s0f - m0;
        const float d1 = s1f - m1;
        w[4 + a] = __expf(n2 * fmaf(d1, d1, d0 * d0));
        packed[4 + a] = ((uint32_t)(int)s0f << 16) | (uint32_t)(int)s1f;
    }
    float denom = 0.0f;
    #pragma unroll
    for (int p = 0; p < NP; ++p) denom += w[p] + 1e-6f;
    const float scale = __fdiv_rn(val, denom);
    #pragma unroll
    for (int p = 0; p < NP; ++p) w[p] *= scale;
}

__global__ __launch_bounds__(256) void init_bias_kernel(
    const float4* __restrict__ bias4, float4* __restrict__ y4)
{
    const int i = blockIdx.x * 256 + threadIdx.x;
    y4[i] = bias4[i & 16383];
}

__global__ __launch_bounds__(256) void hyper_scatter(
    const float*  __restrict__ x,
    const float4* __restrict__ res4,
    float*        __restrict__ y)
{
    const int tid = blockIdx.x * 256 + threadIdx.x;
    const int b = tid >> 14;
    uint32_t packed[NP];
    float    w[NP];
    gen_point(res4[tid], (uint32_t)tid, packed, w);
    const float* __restrict__ xrow = x + ((size_t)b << 16);
    float*       __restrict__ yrow = y + ((size_t)b << 16);
    #pragma unroll
    for (int p = 0; p < NP; ++p) {
        const float xv = xrow[packed[p] & 0xFFFFu];
        unsafeAtomicAdd(&yrow[packed[p] >> 16], w[p] * xv);
    }
}

extern "C" void kernel_launch(void* const* d_in, const int* in_sizes, int n_in,
                              void* d_out, int out_size, void* d_ws, size_t ws_size,
                              hipStream_t stream) {
    const float*  x     = (const float*)d_in[0];   // (16, 65536) f32
    const float4* res4  = (const float4*)d_in[1];  // (16, 16384, 4) f32
    const float4* bias4 = (const float4*)d_in[2];  // (65536,) f32
    float* y = (float*)d_out;                      // (16, 65536) f32

    const size_t need_bf16 = (size_t)NB * GPB * DIM * 2;   // 32 MB

    if (ws_size >= need_bf16) {
        uint32_t* part = (uint32_t*)d_ws;
        f1_gen_reduce_bf16<<<NB * GPB, TPB, 0, stream>>>(x, res4, part);
        f2_final_bf16<<<(NB * DIM / 8) / 256, 256, 0, stream>>>(
            (const u32x4*)part, (const f32x8*)bias4, (f32x8*)y);
    } else {
        init_bias_kernel<<<(NB * DIM / 4) / 256, 256, 0, stream>>>(bias4, (float4*)y);
        hyper_scatter<<<(NB * NK) / 256, 256, 0, stream>>>(x, res4, y);
    }
}

// Round 5
// 152.179 us; speedup vs baseline: 1.0274x; 1.0274x over previous
//
#include <hip/hip_runtime.h>
#include <stdint.h>
#include <math.h>

// Problem constants (from reference)
#define NB 16
#define NK 16384
#define NADD 32
#define NP 36            // 2^RANK + ADD = 4 + 32
#define DIM 65536        // IN_DIM == OUT_DIM

// Round-18: REVERT to round-2 geometry (512 blocks x 512 threads, 64 KB LDS,
// 2 blocks/CU) -- round-4 showed 1 block/CU loses inter-block barrier
// overlap (+6.5 us). NEW: pin amdgpu_waves_per_eu(4,4) so the register
// allocator targets the full 128-VGPR budget that 4 waves/SIMD permits.
// Evidence: VGPR_Count=64 every round while packed[36]+w[36]+xv[36] ~ 90-110
// live values => spills to scratch; FETCH_SIZE ~20 MB vs ~8.3 MB of real
// inputs = spill traffic. 128 VGPRs hold the arrays; spills vanish.
#define TPB 512
#define GPB2 32          // groups per batch row (NK / TPB)
#define NCH3 4           // output chunks per batch row
#define CHW3 16384       // chunk width (floats) -> 64 KB LDS accumulator

typedef float f32x4 __attribute__((ext_vector_type(4)));
typedef float f32x8 __attribute__((ext_vector_type(8)));
typedef unsigned int u32x2 __attribute__((ext_vector_type(2)));
typedef unsigned int u32x4 __attribute__((ext_vector_type(4)));

// LDS-only barrier: orders DS ops without draining vmcnt -- global partial
// stores have no intra-kernel consumer, so they stay in flight across passes.
#define BAR_LGKM() asm volatile("s_waitcnt lgkmcnt(0)\n\ts_barrier" ::: "memory")

__device__ __forceinline__ uint32_t rotl32(uint32_t x, uint32_t r) {
    return (x << r) | (x >> (32u - r));
}

// Threefry-2x32 (20 rounds), key = (0, 42); partitionable mode: ctr=(0,idx),
// bits = out0 ^ out1. CONFIRMED bit-correct (rounds 1-17). INDEX-CRITICAL:
// do not touch.
__device__ __forceinline__ uint32_t tf_bits(uint32_t idx) {
    const uint32_t K1 = 42u;
    const uint32_t K2 = 0x1BD11BDAu ^ 42u;
    uint32_t x0 = 0u;
    uint32_t x1 = idx + K1;
#define TF_ROUND(r) { x0 += x1; x1 = rotl32(x1, r); x1 ^= x0; }
#define TF_G(a,b,c,d) TF_ROUND(a) TF_ROUND(b) TF_ROUND(c) TF_ROUND(d)
    TF_G(13,15,26,6)   x0 += K1;  x1 += K2 + 1u;
    TF_G(17,29,16,24)  x0 += K2;  x1 += 2u;
    TF_G(13,15,26,6)              x1 += K1 + 3u;
    TF_G(17,29,16,24)  x0 += K1;  x1 += K2 + 4u;
    TF_G(13,15,26,6)   x0 += K2;  x1 += 5u;
#undef TF_G
#undef TF_ROUND
    return x0 ^ x1;
}

// Bit-exact XLA:CPU f32 exp (Cephes/Eigen pexp), strict per-op f32 rounding,
// no FMA contraction. CONFIRMED: rounds 3-17 passed. INDEX-CRITICAL (feeds
// sigmoid -> means -> floor/ceil indices): do not touch.
__device__ __forceinline__ float xla_expf(float x0) {
    float x = fminf(fmaxf(x0, -88.3762626647949f), 88.3762626647950f);
    const float fx = floorf(__fadd_rn(__fmul_rn(x, 1.44269504088896341f), 0.5f));
    const float tmp = __fmul_rn(fx, 0.693359375f);
    float z = __fmul_rn(fx, -2.12194440e-4f);
    float r = __fsub_rn(x, tmp);
    r = __fsub_rn(r, z);
    z = __fmul_rn(r, r);
    float y = 1.9875691500E-4f;
    y = __fadd_rn(__fmul_rn(y, r), 1.3981999507E-3f);
    y = __fadd_rn(__fmul_rn(y, r), 8.3334519073E-3f);
    y = __fadd_rn(__fmul_rn(y, r), 4.1665795894E-2f);
    y = __fadd_rn(__fmul_rn(y, r), 1.6666665459E-1f);
    y = __fadd_rn(__fmul_rn(y, r), 5.0000001201E-1f);
    y = __fadd_rn(__fmul_rn(y, z), r);
    y = __fadd_rn(y, 1.0f);
    const int n = (int)fx;
    const float p2n = __uint_as_float((uint32_t)(n + 127) << 23);
    return fmaxf(__fmul_rn(y, p2n), x0);
}

// bf16 RNE pack of two f32 into one u32 (a -> low 16, b -> high 16)
__device__ __forceinline__ uint32_t bf16pair(float a, float b) {
    uint32_t ua = __float_as_uint(a), ub = __float_as_uint(b);
    ua = (ua + 0x7FFFu + ((ua >> 16) & 1u)) >> 16;
    ub = (ub + 0x7FFFu + ((ub >> 16) & 1u)) >> 16;
    return ua | (ub << 16);
}

// ------- primary: 512x512, 64 KB LDS (4 passes), bf16 partials (64 MB) ----
// Partial layout: row = DIM bf16 = 32768 u32 -> row offset = blk << 15 (u32);
// chunk c = 16384 bf16 = 8192 u32 = 4096 u32x2.

__global__ __attribute__((amdgpu_waves_per_eu(4, 4)))
__launch_bounds__(TPB) void f1_gen_reduce_bf16(
    const float*  __restrict__ x,     // (NB, DIM)
    const float4* __restrict__ res4,  // (NB, NK, 4)
    uint32_t* __restrict__ part)      // [NB*GPB2][DIM] bf16
{
    __shared__ float acc[CHW3];       // 64 KB -> 2 blocks/CU (128 KB)
    f32x4* const acc4 = reinterpret_cast<f32x4*>(acc);
    const int blk = blockIdx.x;
    const uint32_t tid = (uint32_t)blk * TPB + threadIdx.x;  // global point id
    const int b = (int)(tid >> 14);
    const float* __restrict__ xrow = x + ((size_t)b << 16);

    // zero LDS up front so the pre-scatter barrier costs nothing
    #pragma unroll
    for (int j = 0; j < 8; ++j)
        acc4[j * TPB + threadIdx.x] = (f32x4)(0.0f);

    const float4 r = res4[tid];

    // ---- index-critical means ----
    const float e0 = xla_expf(-r.x);
    const float e1 = xla_expf(-r.y);
    const float s0 = __fdiv_rn(1.0f, __fadd_rn(1.0f, e0));
    const float s1 = __fdiv_rn(1.0f, __fadd_rn(1.0f, e1));
    const float m0 = __fmul_rn(s0, 65535.0f);   // INDEX-CRITICAL
    const float m1 = __fmul_rn(s1, 65535.0f);   // INDEX-CRITICAL

    // sigma feeds weights only -> relaxed transcendentals
    const float a2 = r.z + 2.0f;
    const float sp = fmaxf(a2, 0.0f) + log1pf(__expf(-fabsf(a2)));
    const float sigma = (sp + 1e-6f) * 65536.0f;
    const float inv_sig = __builtin_amdgcn_rcpf(sigma);
    const float n2 = -0.5f * inv_sig * inv_sig;
    const float val = r.w;

    uint32_t packed[NP];   // (out16 << 16) | in16
    float    xv[NP];       // gathered x values, issued as indices appear

    // corners: indices + immediate gather issue
    {
        const float f0 = floorf(m0), c0 = ceilf(m0);
        const float f1v = floorf(m1), c1 = ceilf(m1);
        const uint32_t uf0 = (uint32_t)(int)f0, uc0 = (uint32_t)(int)c0;
        const uint32_t uf1 = (uint32_t)(int)f1v, uc1 = (uint32_t)(int)c1;
        packed[0] = (uf0 << 16) | uf1;  xv[0] = xrow[uf1];
        packed[1] = (uf0 << 16) | uc1;  xv[1] = xrow[uc1];
        packed[2] = (uc0 << 16) | uf1;  xv[2] = xrow[uf1];
        packed[3] = (uc0 << 16) | uc1;  xv[3] = xrow[uc1];
    }

    // sampled tuples: threefry VALU work hides each gather's latency
    const float ONE_MEPS = (float)(1.0 - 1e-6);
    const uint32_t base = tid * 64u;
    #pragma unroll
    for (int a = 0; a < NADD; ++a) {
        const uint32_t bb0 = tf_bits(base + 2u*(uint32_t)a);
        const uint32_t bb1 = tf_bits(base + 2u*(uint32_t)a + 1u);
        const float u0 = __fmul_rn(__uint_as_float((bb0 >> 9) | 0x3f800000u) - 1.0f, ONE_MEPS);
        const float u1 = __fmul_rn(__uint_as_float((bb1 >> 9) | 0x3f800000u) - 1.0f, ONE_MEPS);
        const float s0f = floorf(__fmul_rn(u0, 65536.0f));  // INDEX-CRITICAL
        const float s1f = floorf(__fmul_rn(u1, 65536.0f));  // INDEX-CRITICAL
        const uint32_t pi = ((uint32_t)(int)s0f << 16) | (uint32_t)(int)s1f;
        packed[4 + a] = pi;
        xv[4 + a] = xrow[pi & 0xFFFFu];
    }

    // exp pass: denom uses raw e (same order as passing kernels); xv folds
    // in immediately so its registers die here.
    float w[NP];
    float denom = 0.0f;
    #pragma unroll
    for (int p = 0; p < NP; ++p) {
        const float d0 = (float)(int)(packed[p] >> 16) - m0;
        const float d1 = (float)(int)(packed[p] & 0xFFFFu) - m1;
        const float e = __expf(n2 * fmaf(d1, d1, d0 * d0));
        denom += e + 1e-6f;
        w[p] = e * xv[p];
    }
    const float scale = __fdiv_rn(val, denom);
    #pragma unroll
    for (int p = 0; p < NP; ++p) w[p] *= scale;

    __syncthreads();   // zeros visible; no global stores outstanding yet

    uint32_t* __restrict__ dst = part + ((size_t)blk << 15);  // u32 row
    #pragma unroll 1
    for (uint32_t c = 0; c < NCH3; ++c) {
        #pragma unroll
        for (int p = 0; p < NP; ++p) {
            if ((packed[p] >> 30) == c)
                atomicAdd(&acc[(packed[p] >> 16) & (CHW3 - 1)], w[p]);
        }
        BAR_LGKM();   // DS atomics drained; global stores may stay in flight
        // merged drain: pack bf16, cacheable store, re-zero in one sweep.
        u32x2* __restrict__ dst2 =
            reinterpret_cast<u32x2*>(dst + (size_t)c * 8192);
        #pragma unroll
        for (int j = 0; j < 8; ++j) {
            const int idx = j * TPB + (int)threadIdx.x;   // [0, 4096) u32x2
            const f32x4 v = acc4[idx];
            const u32x2 o = { bf16pair(v.x, v.y), bf16pair(v.z, v.w) };
            dst2[idx] = o;                                // LLC-resident
            acc4[idx] = (f32x4)(0.0f);                    // re-zero for next pass
        }
        BAR_LGKM();   // re-zeros visible; stores not drained
    }
    // kernel-end release flushes outstanding stores before f2 launches
}

// F2: y = bias + sum_g bf16 part rows; fully coalesced. UNCHANGED from
// round 2 (clean A/B isolation of the f1 regalloc change).
__global__ __launch_bounds__(256) void f2_final_bf16(
    const u32x4* __restrict__ part4,  // [NB*GPB2][8192] u32x4
    const f32x8* __restrict__ bias8,  // 8192 x f32x8
    f32x8* __restrict__ y8)           // NB*8192 x f32x8
{
    const int i = blockIdx.x * 256 + threadIdx.x;  // [0, NB*DIM/8)
    const int o8 = i & 8191;                       // u32x4 index within row
    const int b = i >> 13;
    f32x8 s = bias8[o8];
    #pragma unroll
    for (int g = 0; g < GPB2; ++g) {
        const u32x4 p = part4[(((size_t)(b * GPB2 + g)) << 13) + o8];
        s[0] += __uint_as_float(p.x << 16);
        s[1] += __uint_as_float(p.x & 0xFFFF0000u);
        s[2] += __uint_as_float(p.y << 16);
        s[3] += __uint_as_float(p.y & 0xFFFF0000u);
        s[4] += __uint_as_float(p.z << 16);
        s[5] += __uint_as_float(p.z & 0xFFFF0000u);
        s[6] += __uint_as_float(p.w << 16);
        s[7] += __uint_as_float(p.w & 0xFFFF0000u);
    }
    __builtin_nontemporal_store(s, &y8[i]);
}

// ---------------- fallback path (round-3 passing kernel) ----------------

__device__ __forceinline__ void gen_point(const float4 r, uint32_t tid,
                                          uint32_t* packed, float* w) {
    const float e0 = xla_expf(-r.x);
    const float e1 = xla_expf(-r.y);
    const float s0 = __fdiv_rn(1.0f, __fadd_rn(1.0f, e0));
    const float s1 = __fdiv_rn(1.0f, __fadd_rn(1.0f, e1));
    const float m0 = __fmul_rn(s0, 65535.0f);
    const float m1 = __fmul_rn(s1, 65535.0f);
    const float a2 = r.z + 2.0f;
    const float sp = fmaxf(a2, 0.0f) + log1pf(__expf(-fabsf(a2)));
    const float sigma = (sp + 1e-6f) * 65536.0f;
    const float inv_sig = __builtin_amdgcn_rcpf(sigma);
    const float n2 = -0.5f * inv_sig * inv_sig;
    const float val = r.w;

    const float f0 = floorf(m0), c0 = ceilf(m0);
    const float f1 = floorf(m1), c1 = ceilf(m1);
    {
        const float cd0[4] = {f0, f0, c0, c0};
        const float cd1[4] = {f1, c1, f1, c1};
        #pragma unroll
        for (int p = 0; p < 4; ++p) {
            const float d0 = cd0[p] - m0;
            const float d1 = cd1[p] - m1;
            w[p] = __expf(n2 * fmaf(d1, d1, d0 * d0));
            packed[p] = ((uint32_t)(int)cd0[p] << 16) | (uint32_t)(int)cd1[p];
        }
    }
    const float ONE_MEPS = (float)(1.0 - 1e-6);
    const uint32_t base = tid * 64u;
    #pragma unroll
    for (int a = 0; a < NADD; ++a) {
        const uint32_t bb0 = tf_bits(base + 2u*(uint32_t)a);
        const uint32_t bb1 = tf_bits(base + 2u*(uint32_t)a + 1u);
        const float u0 = __fmul_rn(__uint_as_float((bb0 >> 9) | 0x3f800000u) - 1.0f, ONE_MEPS);
        const float u1 = __fmul_rn(__uint_as_float((bb1 >> 9) | 0x3f800000u) - 1.0f, ONE_MEPS);
        const float s0f = floorf(__fmul_rn(u0, 65536.0f));
        const float s1f = floorf(__fmul_rn(u1, 65536.0f));
        const float d0 = s0f - m0;
        const float d1 = s1f - m1;
        w[4 + a] = __expf(n2 * fmaf(d1, d1, d0 * d0));
        packed[4 + a] = ((uint32_t)(int)s0f << 16) | (uint32_t)(int)s1f;
    }
    float denom = 0.0f;
    #pragma unroll
    for (int p = 0; p < NP; ++p) denom += w[p] + 1e-6f;
    const float scale = __fdiv_rn(val, denom);
    #pragma unroll
    for (int p = 0; p < NP; ++p) w[p] *= scale;
}

__global__ __launch_bounds__(256) void init_bias_kernel(
    const float4* __restrict__ bias4, float4* __restrict__ y4)
{
    const int i = blockIdx.x * 256 + threadIdx.x;
    y4[i] = bias4[i & 16383];
}

__global__ __launch_bounds__(256) void hyper_scatter(
    const float*  __restrict__ x,
    const float4* __restrict__ res4,
    float*        __restrict__ y)
{
    const int tid = blockIdx.x * 256 + threadIdx.x;
    const int b = tid >> 14;
    uint32_t packed[NP];
    float    w[NP];
    gen_point(res4[tid], (uint32_t)tid, packed, w);
    const float* __restrict__ xrow = x + ((size_t)b << 16);
    float*       __restrict__ yrow = y + ((size_t)b << 16);
    #pragma unroll
    for (int p = 0; p < NP; ++p) {
        const float xv = xrow[packed[p] & 0xFFFFu];
        unsafeAtomicAdd(&yrow[packed[p] >> 16], w[p] * xv);
    }
}

extern "C" void kernel_launch(void* const* d_in, const int* in_sizes, int n_in,
                              void* d_out, int out_size, void* d_ws, size_t ws_size,
                              hipStream_t stream) {
    const float*  x     = (const float*)d_in[0];   // (16, 65536) f32
    const float4* res4  = (const float4*)d_in[1];  // (16, 16384, 4) f32
    const float4* bias4 = (const float4*)d_in[2];  // (65536,) f32
    float* y = (float*)d_out;                      // (16, 65536) f32

    const size_t need_bf16 = (size_t)NB * GPB2 * DIM * 2;   // 64 MB

    if (ws_size >= need_bf16) {
        uint32_t* part = (uint32_t*)d_ws;
        f1_gen_reduce_bf16<<<NB * GPB2, TPB, 0, stream>>>(x, res4, part);
        f2_final_bf16<<<(NB * DIM / 8) / 256, 256, 0, stream>>>(
            (const u32x4*)part, (const f32x8*)bias4, (f32x8*)y);
    } else {
        init_bias_kernel<<<(NB * DIM / 4) / 256, 256, 0, stream>>>(bias4, (float4*)y);
        hyper_scatter<<<(NB * NK) / 256, 256, 0, stream>>>(x, res4, y);
    }
}